// Round 3
// baseline (211.739 us; speedup 1.0000x reference)
//
#include <hip/hip_runtime.h>
#include <hip/hip_bf16.h>

#define NB 4
#define NC 256
#define NN 4096
#define NCR 32
#define PITCH 136   // shorts; 272B rows -> bank = (4*lm + c) % 32, 2-way max

typedef __attribute__((ext_vector_type(8))) short short8_t;
typedef __attribute__((ext_vector_type(4))) float f32x4;
typedef __attribute__((ext_vector_type(2))) int int2_t;
typedef __attribute__((ext_vector_type(4))) int int4_t;
typedef __attribute__((ext_vector_type(4))) float float4_t;

static __device__ __forceinline__ unsigned short f2bf(float f) {
  unsigned u = __builtin_bit_cast(unsigned, f);
  u += 0x7FFFu + ((u >> 16) & 1u);
  return (unsigned short)(u >> 16);
}

static __device__ __forceinline__ unsigned cvt_pk(float lo, float hi) {
  unsigned r;
  asm("v_cvt_pk_bf16_f32 %0, %1, %2" : "=v"(r) : "v"(lo), "v"(hi));
  return r;
}

// ---------------------------------------------------------------------------
// Kernel 0: one-time W pack f32 -> bf16. rows [0,32)=Wq, [32,64)=Wk, [64,320)=Wv
// ---------------------------------------------------------------------------
__global__ __launch_bounds__(64) void pack_w_kernel(
    const float* __restrict__ Wq, const float* __restrict__ Wk,
    const float* __restrict__ Wv, unsigned short* __restrict__ Wbf)
{
  const int row = blockIdx.x;
  const int t = threadIdx.x;
  const float* src = row < 32 ? Wq + (size_t)row * NC
                   : (row < 64 ? Wk + (size_t)(row - 32) * NC
                               : Wv + (size_t)(row - 64) * NC);
  float4_t v = *(const float4_t*)(src + t * 4);
  int2_t p;
  p[0] = cvt_pk(v[0], v[1]);
  p[1] = cvt_pk(v[2], v[3]);
  *(int2_t*)(Wbf + (size_t)row * NC + t * 4) = p;
}

// ---------------------------------------------------------------------------
// Kernel 1: QKV projection. BM=32, grid 512 = batch(4) x m-tile(128) -> 2
// blocks/CU (8 waves/CU). x chunk (64k x 32m) staged in LDS bf16, XOR-swizzled.
// Swapped MFMA: D^T[m][d] so V stores are b64 along n.
// ---------------------------------------------------------------------------
__global__ __launch_bounds__(256, 2) void qkv_kernel(
    const float* __restrict__ x, const unsigned short* __restrict__ Wbf,
    const float* __restrict__ bq, const float* __restrict__ bk,
    const float* __restrict__ bv,
    unsigned short* __restrict__ Qt, unsigned short* __restrict__ Kt,
    unsigned short* __restrict__ Vt)
{
  __shared__ unsigned short xT[2][32 * 64];  // [buf][m][k-unit swizzled], 4KB

  const int bid = blockIdx.x;
  const int b   = bid >> 7;
  const int m0  = (bid & 127) * 32;
  const int tid = threadIdx.x;
  const int w    = tid >> 6;
  const int lane = tid & 63;
  const int lg   = lane >> 4;
  const int lm   = lane & 15;

  // x loader mapping: column m0+mcol, k-rows kg*8..+8 per 64-k chunk
  const int mcol = tid & 31, kg = tid >> 5;
  const float* xld = x + (size_t)b * NC * NN + (size_t)(kg * 8) * NN + m0 + mcol;
  const int wofs = mcol * 64 + ((kg ^ (mcol & 7)) << 3);  // short index
  const unsigned short* wrow = Wbf + (size_t)(w * 80 + lm) * NC;

  const f32x4 zero4 = {0.f, 0.f, 0.f, 0.f};
  f32x4 acc[5][2];
#pragma unroll
  for (int df = 0; df < 5; df++)
#pragma unroll
    for (int mf = 0; mf < 2; mf++) acc[df][mf] = zero4;

  float xg[8], xn[8];
#pragma unroll
  for (int j = 0; j < 8; j++) xg[j] = xld[(size_t)j * NN];

#define QCHUNK(C, XC, XN, BUF) {                                              \
    if ((C) < 3) {                                                            \
      _Pragma("unroll") for (int j = 0; j < 8; j++)                           \
        XN[j] = xld[(size_t)(((C) + 1) * 64 + j) * NN];                       \
    }                                                                         \
    int4_t xwv;                                                               \
    xwv[0] = cvt_pk(XC[0], XC[1]); xwv[1] = cvt_pk(XC[2], XC[3]);             \
    xwv[2] = cvt_pk(XC[4], XC[5]); xwv[3] = cvt_pk(XC[6], XC[7]);             \
    *(int4_t*)(&xT[BUF][wofs]) = xwv;                                         \
    __syncthreads();                                                          \
    _Pragma("unroll") for (int ks = 0; ks < 2; ks++) {                        \
      short8_t xf[2];                                                         \
      _Pragma("unroll") for (int mf = 0; mf < 2; mf++) {                      \
        const int row = mf * 16 + lm;                                         \
        const int unit = (ks * 4 + lg) ^ (lm & 7);                            \
        xf[mf] = *(const short8_t*)(&xT[BUF][row * 64 + unit * 8]);           \
      }                                                                       \
      _Pragma("unroll") for (int df = 0; df < 5; df++) {                      \
        const short8_t wf = *(const short8_t*)(wrow + (size_t)df * 16 * NC +  \
                                               (C) * 64 + ks * 32 + lg * 8);  \
        _Pragma("unroll") for (int mf = 0; mf < 2; mf++)                      \
          acc[df][mf] = __builtin_amdgcn_mfma_f32_16x16x32_bf16(              \
              xf[mf], wf, acc[df][mf], 0, 0, 0);                              \
      }                                                                       \
    }                                                                         \
  }

  QCHUNK(0, xg, xn, 0)
  QCHUNK(1, xn, xg, 1)
  QCHUNK(2, xg, xn, 0)
  QCHUNK(3, xn, xg, 1)
#undef QCHUNK

  // Epilogue: acc[df][mf][i] = D^T[m = m0+mf*16+4lg+i][d = w*80+df*16+lm]
#pragma unroll
  for (int df = 0; df < 5; df++) {
    const int dbase = w * 80 + df * 16;
    if (dbase < 64) {
      const bool isq = dbase < 32;
      const float bia = isq ? bq[dbase + lm] : bk[dbase - 32 + lm];
      unsigned short* dst = isq ? Qt : Kt;
      const int dcol = (isq ? dbase : dbase - 32) + lm;
#pragma unroll
      for (int mf = 0; mf < 2; mf++)
#pragma unroll
        for (int i = 0; i < 4; i++) {
          const int m = m0 + mf * 16 + lg * 4 + i;
          dst[((size_t)b * NN + m) * NCR + dcol] = f2bf(acc[df][mf][i] + bia);
        }
    } else {
      const int c = dbase - 64 + lm;
      const float bia = bv[c];
#pragma unroll
      for (int mf = 0; mf < 2; mf++) {
        int2_t p;
        p[0] = cvt_pk(acc[df][mf][0] + bia, acc[df][mf][1] + bia);
        p[1] = cvt_pk(acc[df][mf][2] + bia, acc[df][mf][3] + bia);
        *(int2_t*)(Vt + ((size_t)b * NC + c) * NN + m0 + mf * 16 + lg * 4) = p;
      }
    }
  }
}

// ---------------------------------------------------------------------------
// Kernel 2: streaming attention, 8 waves. n-tile 128/iter (32 iters).
// Wave w: S rows [16w,16w+16); PV: c-group (w&3)*64, n-half (w>>2)*64.
// Pair (w, w+4) accs merged via LDS at end; epilogue split across all waves.
// ---------------------------------------------------------------------------
__global__ __launch_bounds__(512, 2) void attn_kernel(
    const unsigned short* __restrict__ Qt, const unsigned short* __restrict__ Kt,
    const unsigned short* __restrict__ Vt, const float* __restrict__ x,
    const float* __restrict__ gamma, float* __restrict__ out)
{
  __shared__ unsigned short Slds[2][64 * PITCH];  // 34.8 KB: S^T [m][n 0..128)
  __shared__ float mbuf[4][64][17];               // 17.4 KB merge buffer
  __shared__ float dlds[8][64];                   // 2 KB

  int bid = blockIdx.x;
  bid = (bid & 7) * 32 + (bid >> 3);  // bijective XCD swizzle (2 XCDs/batch)
  const int b   = bid >> 6;
  const int m0  = (bid & 63) * 64;
  const int tid = threadIdx.x;
  const int w    = tid >> 6;     // 0..7
  const int lane = tid & 63;
  const int lg   = lane >> 4;
  const int lm   = lane & 15;
  const int cg   = w & 3;        // c-group (64 rows)
  const int nh   = w >> 2;       // n-half of the 128-tile

  const unsigned short* Qb = Qt + (size_t)b * NN * NCR;
  const unsigned short* Kp = Kt + (size_t)b * NN * NCR +
                             (size_t)(w * 16 + lm) * NCR + lg * 8;
  const unsigned short* Vb = Vt + (size_t)b * NC * NN;
  const unsigned short* pV[4];
#pragma unroll
  for (int cf = 0; cf < 4; cf++)
    pV[cf] = Vb + (size_t)(cg * 64 + cf * 16 + lm) * NN + nh * 64 + lg * 8;

  short8_t qf[4];
#pragma unroll
  for (int mf = 0; mf < 4; mf++)
    qf[mf] = *(const short8_t*)(Qb + (size_t)(m0 + mf * 16 + lm) * NCR + lg * 8);

  const f32x4 zero4 = {0.f, 0.f, 0.f, 0.f};
  f32x4 acc[4][4];
#pragma unroll
  for (int cf = 0; cf < 4; cf++)
#pragma unroll
    for (int mf = 0; mf < 4; mf++) acc[cf][mf] = zero4;
  float dsum[4] = {0.f, 0.f, 0.f, 0.f};

  // prologue: tile 0 fragments
  short8_t kA, kB, vA[4][2], vB[4][2];
  kA = *(const short8_t*)(Kp);
#pragma unroll
  for (int cf = 0; cf < 4; cf++)
#pragma unroll
    for (int nch = 0; nch < 2; nch++)
      vA[cf][nch] = *(const short8_t*)(pV[cf] + nch * 32);

  const int swofs = w * 16 + lg * 4;  // this wave's S n-offset

#define AITER(T, KC, KN, VC, VN, BUF) {                                       \
    const int n1 = (((T) + 1) & 31) * 128;                                    \
    KN = *(const short8_t*)(Kp + (size_t)n1 * NCR);                           \
    _Pragma("unroll") for (int cf = 0; cf < 4; cf++)                          \
      _Pragma("unroll") for (int nch = 0; nch < 2; nch++)                     \
        VN[cf][nch] = *(const short8_t*)(pV[cf] + n1 + nch * 32);             \
    _Pragma("unroll") for (int mf = 0; mf < 4; mf++) {                        \
      f32x4 s = __builtin_amdgcn_mfma_f32_16x16x32_bf16(KC, qf[mf], zero4, 0, 0, 0); \
      float s0 = fmaxf(s[0], 0.f), s1 = fmaxf(s[1], 0.f);                     \
      float s2 = fmaxf(s[2], 0.f), s3 = fmaxf(s[3], 0.f);                     \
      dsum[mf] += (s0 + s1) + (s2 + s3);                                      \
      int2_t p; p[0] = cvt_pk(s0, s1); p[1] = cvt_pk(s2, s3);                 \
      *(int2_t*)(&Slds[BUF][(mf * 16 + lm) * PITCH + swofs]) = p;             \
    }                                                                         \
    __syncthreads();                                                          \
    __builtin_amdgcn_s_setprio(1);                                            \
    _Pragma("unroll") for (int nch = 0; nch < 2; nch++) {                     \
      short8_t sf[4];                                                         \
      _Pragma("unroll") for (int mf = 0; mf < 4; mf++)                        \
        sf[mf] = *(const short8_t*)(&Slds[BUF][(mf * 16 + lm) * PITCH +       \
                                              nh * 64 + nch * 32 + lg * 8]);  \
      _Pragma("unroll") for (int cf = 0; cf < 4; cf++)                        \
        _Pragma("unroll") for (int mf = 0; mf < 4; mf++)                      \
          acc[cf][mf] = __builtin_amdgcn_mfma_f32_16x16x32_bf16(              \
              VC[cf][nch], sf[mf], acc[cf][mf], 0, 0, 0);                     \
    }                                                                         \
    __builtin_amdgcn_s_setprio(0);                                            \
  }

#pragma unroll 1
  for (int t = 0; t < 32; t += 2) {
    AITER(t, kA, kB, vA, vB, 0)
    AITER(t + 1, kB, kA, vB, vA, 1)
  }
#undef AITER

  // denominator: reduce over lg groups, publish per wave
#pragma unroll
  for (int mf = 0; mf < 4; mf++) {
    float v = dsum[mf];
    v += __shfl_xor(v, 16);
    v += __shfl_xor(v, 32);
    if (lane < 16) dlds[w][mf * 16 + lane] = v;
  }

  // merge acc pairs (w, w+4): cf 0,1 -> low waves; cf 2,3 -> high waves
#pragma unroll
  for (int cf = 0; cf < 2; cf++) {
    if (w >= 4) {
#pragma unroll
      for (int mf = 0; mf < 4; mf++)
#pragma unroll
        for (int i = 0; i < 4; i++) mbuf[w - 4][lane][mf * 4 + i] = acc[cf][mf][i];
    }
    __syncthreads();
    if (w < 4) {
#pragma unroll
      for (int mf = 0; mf < 4; mf++)
#pragma unroll
        for (int i = 0; i < 4; i++) acc[cf][mf][i] += mbuf[w][lane][mf * 4 + i];
    }
    __syncthreads();
  }
#pragma unroll
  for (int cf = 2; cf < 4; cf++) {
    if (w < 4) {
#pragma unroll
      for (int mf = 0; mf < 4; mf++)
#pragma unroll
        for (int i = 0; i < 4; i++) mbuf[w][lane][mf * 4 + i] = acc[cf][mf][i];
    }
    __syncthreads();
    if (w >= 4) {
#pragma unroll
      for (int mf = 0; mf < 4; mf++)
#pragma unroll
        for (int i = 0; i < 4; i++) acc[cf][mf][i] += mbuf[w - 4][lane][mf * 4 + i];
    }
    __syncthreads();
  }

  const float g0 = gamma[0];
  float rden[4];
#pragma unroll
  for (int mf = 0; mf < 4; mf++) {
    const int mloc = mf * 16 + lm;
    float den = 0.f;
#pragma unroll
    for (int ww = 0; ww < 8; ww++) den += dlds[ww][mloc];
    den = den > 1e-12f ? den : 1e-12f;
    rden[mf] = 1.0f / den;
  }

  // epilogue: wave writes its 2 merged cf tiles (w<4: cf 0,1; w>=4: cf 2,3)
  const int cf0 = (w >> 2) * 2;
  const float* xb = x + (size_t)b * NC * NN;
  float* ob = out + (size_t)b * NC * NN;
#pragma unroll
  for (int cfo = 0; cfo < 2; cfo++) {
    const int cf = cf0 + cfo;
#pragma unroll
    for (int i = 0; i < 4; i++) {
      const int c = cg * 64 + cf * 16 + lg * 4 + i;
#pragma unroll
      for (int mf = 0; mf < 4; mf++) {
        const int m = m0 + mf * 16 + lm;
        ob[(size_t)c * NN + m] = g0 * acc[cf][mf][i] * rden[mf] + xb[(size_t)c * NN + m];
      }
    }
  }
}

extern "C" void kernel_launch(void* const* d_in, const int* in_sizes, int n_in,
                              void* d_out, int out_size, void* d_ws, size_t ws_size,
                              hipStream_t stream) {
  const float* x     = (const float*)d_in[0];
  const float* Wq    = (const float*)d_in[1];
  const float* bq    = (const float*)d_in[2];
  const float* Wk    = (const float*)d_in[3];
  const float* bk    = (const float*)d_in[4];
  const float* Wv    = (const float*)d_in[5];
  const float* bv    = (const float*)d_in[6];
  const float* gamma = (const float*)d_in[7];
  float* out = (float*)d_out;

  unsigned short* Wbf = (unsigned short*)d_ws;
  unsigned short* Qt  = Wbf + (size_t)320 * NC;
  unsigned short* Kt  = Qt + (size_t)NB * NN * NCR;
  unsigned short* Vt  = Kt + (size_t)NB * NN * NCR;

  hipLaunchKernelGGL(pack_w_kernel, dim3(320), dim3(64), 0, stream,
                     Wq, Wk, Wv, Wbf);
  hipLaunchKernelGGL(qkv_kernel, dim3(512), dim3(256), 0, stream,
                     x, Wbf, bq, bk, bv, Qt, Kt, Vt);
  hipLaunchKernelGGL(attn_kernel, dim3(256), dim3(512), 0, stream,
                     Qt, Kt, Vt, x, gamma, out);
}

// Round 4
// 102.318 us; speedup vs baseline: 2.0694x; 2.0694x over previous
//
#include <hip/hip_runtime.h>
#include <hip/hip_bf16.h>

#define NB 4
#define NC 256
#define NN 4096
#define NCR 32
#define PITCH 72   // shorts; 144B rows -> 2-way max aliasing (free per m136)

typedef __attribute__((ext_vector_type(8))) short short8_t;
typedef __attribute__((ext_vector_type(4))) float f32x4;
typedef __attribute__((ext_vector_type(2))) int int2_t;
typedef __attribute__((ext_vector_type(4))) int int4_t;
typedef __attribute__((ext_vector_type(4))) float float4_t;

static __device__ __forceinline__ unsigned short f2bf(float f) {
  unsigned u = __builtin_bit_cast(unsigned, f);
  u += 0x7FFFu + ((u >> 16) & 1u);
  return (unsigned short)(u >> 16);
}

static __device__ __forceinline__ unsigned cvt_pk(float lo, float hi) {
  unsigned r;
  asm("v_cvt_pk_bf16_f32 %0, %1, %2" : "=v"(r) : "v"(lo), "v"(hi));
  return r;
}

// ---------------------------------------------------------------------------
// Kernel 0: one-time W pack f32 -> bf16. rows [0,32)=Wq, [32,64)=Wk, [64,320)=Wv
// ---------------------------------------------------------------------------
__global__ __launch_bounds__(64) void pack_w_kernel(
    const float* __restrict__ Wq, const float* __restrict__ Wk,
    const float* __restrict__ Wv, unsigned short* __restrict__ Wbf)
{
  const int row = blockIdx.x;
  const int t = threadIdx.x;
  const float* src = row < 32 ? Wq + (size_t)row * NC
                   : (row < 64 ? Wk + (size_t)(row - 32) * NC
                               : Wv + (size_t)(row - 64) * NC);
  float4_t v = *(const float4_t*)(src + t * 4);
  int2_t p;
  p[0] = cvt_pk(v[0], v[1]);
  p[1] = cvt_pk(v[2], v[3]);
  *(int2_t*)(Wbf + (size_t)row * NC + t * 4) = p;
}

// ---------------------------------------------------------------------------
// Kernel 0b: transpose+cast x[b][k][m] f32 -> xT[b][m][k] bf16.
// Tile 32k x 64m per block; coalesced read, 16B-chunk write.
// ---------------------------------------------------------------------------
__global__ __launch_bounds__(256) void xpose_kernel(
    const float* __restrict__ x, unsigned short* __restrict__ xT)
{
  __shared__ float tile[32][65];
  const int bid = blockIdx.x;
  const int mt = bid & 63, kt = (bid >> 6) & 7, b = bid >> 9;
  const int m0 = mt * 64, k0 = kt * 32;
  const int tid = threadIdx.x;

  const float* xb = x + (size_t)b * NC * NN + (size_t)k0 * NN + m0;
#pragma unroll
  for (int p = 0; p < 8; p++) {
    const int r = p * 4 + (tid >> 6);
    tile[r][tid & 63] = xb[(size_t)r * NN + (tid & 63)];
  }
  __syncthreads();

  const int m = tid >> 2, kq = (tid & 3) * 8;
  int4_t o;
#pragma unroll
  for (int j = 0; j < 4; j++)
    o[j] = cvt_pk(tile[kq + 2 * j][m], tile[kq + 2 * j + 1][m]);
  *(int4_t*)(xT + ((size_t)b * NN + m0 + m) * NC + k0 + kq) = o;
}

// ---------------------------------------------------------------------------
// Kernel 1: QKV projection — pure streaming GEMM, no LDS.
// D^T[m][d] = xT[m][:] @ W^T; both fragments are contiguous 16B loads.
// Grid 512 = batch(4) x m-tile(128 of 32), 4 waves x 80 d-rows, 2 blocks/CU.
// ---------------------------------------------------------------------------
__global__ __launch_bounds__(256, 2) void qkv_kernel(
    const unsigned short* __restrict__ xT, const unsigned short* __restrict__ Wbf,
    const float* __restrict__ bq, const float* __restrict__ bk,
    const float* __restrict__ bv,
    unsigned short* __restrict__ Qt, unsigned short* __restrict__ Kt,
    unsigned short* __restrict__ Vt)
{
  const int bid = blockIdx.x;
  const int b   = bid >> 7;
  const int m0  = (bid & 127) * 32;
  const int tid = threadIdx.x;
  const int w    = tid >> 6;
  const int lane = tid & 63;
  const int lg   = lane >> 4;
  const int lm   = lane & 15;

  const unsigned short* xrow0 = xT + ((size_t)b * NN + m0 + lm) * NC + lg * 8;
  const unsigned short* xrow1 = xrow0 + 16 * NC;
  const unsigned short* wrow  = Wbf + (size_t)(w * 80 + lm) * NC + lg * 8;

  const f32x4 zero4 = {0.f, 0.f, 0.f, 0.f};
  f32x4 acc[5][2];
#pragma unroll
  for (int df = 0; df < 5; df++)
#pragma unroll
    for (int mf = 0; mf < 2; mf++) acc[df][mf] = zero4;

#pragma unroll
  for (int kc = 0; kc < 8; kc++) {
    const short8_t xf0 = *(const short8_t*)(xrow0 + kc * 32);
    const short8_t xf1 = *(const short8_t*)(xrow1 + kc * 32);
#pragma unroll
    for (int df = 0; df < 5; df++) {
      const short8_t wf = *(const short8_t*)(wrow + (size_t)df * 16 * NC + kc * 32);
      acc[df][0] = __builtin_amdgcn_mfma_f32_16x16x32_bf16(xf0, wf, acc[df][0], 0, 0, 0);
      acc[df][1] = __builtin_amdgcn_mfma_f32_16x16x32_bf16(xf1, wf, acc[df][1], 0, 0, 0);
    }
  }

  // acc[df][mf][i] = D^T[m = m0+mf*16+4lg+i][d = w*80+df*16+lm]
#pragma unroll
  for (int df = 0; df < 5; df++) {
    const int dbase = w * 80 + df * 16;
    if (dbase < 64) {
      const bool isq = dbase < 32;
      const float bia = isq ? bq[dbase + lm] : bk[dbase - 32 + lm];
      unsigned short* dst = isq ? Qt : Kt;
      const int dcol = (isq ? dbase : dbase - 32) + lm;
#pragma unroll
      for (int mf = 0; mf < 2; mf++)
#pragma unroll
        for (int i = 0; i < 4; i++) {
          const int m = m0 + mf * 16 + lg * 4 + i;
          dst[((size_t)b * NN + m) * NCR + dcol] = f2bf(acc[df][mf][i] + bia);
        }
    } else {
      const int c = dbase - 64 + lm;
      const float bia = bv[c];
#pragma unroll
      for (int mf = 0; mf < 2; mf++) {
        int2_t p;
        p[0] = cvt_pk(acc[df][mf][0] + bia, acc[df][mf][1] + bia);
        p[1] = cvt_pk(acc[df][mf][2] + bia, acc[df][mf][3] + bia);
        *(int2_t*)(Vt + ((size_t)b * NC + c) * NN + m0 + mf * 16 + lg * 4) = p;
      }
    }
  }
}

// ---------------------------------------------------------------------------
// Kernel 2: streaming attention, c-split. Grid 512 = batch x m-tile x c-half,
// 4 waves, 2 blocks/CU. Wave w: S rows [16w,16w+16); PV c-rows
// ch*128 + w*32 .. +32. S redundantly computed per c-half (11% of FLOPs).
// V loaded early (single-buffered, latency hidden under S+barrier).
// ---------------------------------------------------------------------------
__global__ __launch_bounds__(256, 2) void attn_kernel(
    const unsigned short* __restrict__ Qt, const unsigned short* __restrict__ Kt,
    const unsigned short* __restrict__ Vt, const float* __restrict__ x,
    const float* __restrict__ gamma, float* __restrict__ out)
{
  __shared__ unsigned short Slds[2][64 * PITCH];  // 18.4 KB
  __shared__ float dlds[4][64];

  const int bid = blockIdx.x;
  const int xcd = bid & 7;
  const int b   = xcd >> 1;          // batch pinned to an XCD pair slot
  const int ch  = xcd & 1;           // c-half
  const int m0  = (bid >> 3) * 64;   // 64 m-tiles per (b, ch)
  const int tid = threadIdx.x;
  const int w    = tid >> 6;
  const int lane = tid & 63;
  const int lg   = lane >> 4;
  const int lm   = lane & 15;

  const unsigned short* Qb = Qt + (size_t)b * NN * NCR;
  const unsigned short* Kp = Kt + (size_t)b * NN * NCR +
                             (size_t)(w * 16 + lm) * NCR + lg * 8;
  const unsigned short* pV[2];
#pragma unroll
  for (int cf = 0; cf < 2; cf++)
    pV[cf] = Vt + ((size_t)b * NC + ch * 128 + w * 32 + cf * 16 + lm) * NN + lg * 8;

  short8_t qf[4];
#pragma unroll
  for (int mf = 0; mf < 4; mf++)
    qf[mf] = *(const short8_t*)(Qb + (size_t)(m0 + mf * 16 + lm) * NCR + lg * 8);

  const f32x4 zero4 = {0.f, 0.f, 0.f, 0.f};
  f32x4 acc[2][4];
#pragma unroll
  for (int cf = 0; cf < 2; cf++)
#pragma unroll
    for (int mf = 0; mf < 4; mf++) acc[cf][mf] = zero4;
  float dsum[4] = {0.f, 0.f, 0.f, 0.f};

  short8_t kA, kB;
  kA = *(const short8_t*)(Kp);

  const int swofs = w * 16 + lg * 4;

#define AITER(T, KC, KN, BUF) {                                               \
    const int ncur = (T) * 64;                                                \
    /* V loads for THIS tile issued first: latency hides under S+barrier */   \
    short8_t vc[2][2];                                                        \
    _Pragma("unroll") for (int cf = 0; cf < 2; cf++) {                        \
      vc[cf][0] = *(const short8_t*)(pV[cf] + ncur);                          \
      vc[cf][1] = *(const short8_t*)(pV[cf] + ncur + 32);                     \
    }                                                                         \
    const int n1 = (((T) + 1) & 63) * 64;                                     \
    KN = *(const short8_t*)(Kp + (size_t)n1 * NCR);                           \
    _Pragma("unroll") for (int mf = 0; mf < 4; mf++) {                        \
      f32x4 s = __builtin_amdgcn_mfma_f32_16x16x32_bf16(KC, qf[mf], zero4, 0, 0, 0); \
      float s0 = fmaxf(s[0], 0.f), s1 = fmaxf(s[1], 0.f);                     \
      float s2 = fmaxf(s[2], 0.f), s3 = fmaxf(s[3], 0.f);                     \
      dsum[mf] += (s0 + s1) + (s2 + s3);                                      \
      int2_t p; p[0] = cvt_pk(s0, s1); p[1] = cvt_pk(s2, s3);                 \
      *(int2_t*)(&Slds[BUF][(mf * 16 + lm) * PITCH + swofs]) = p;             \
    }                                                                         \
    __syncthreads();                                                          \
    __builtin_amdgcn_s_setprio(1);                                            \
    _Pragma("unroll") for (int nch = 0; nch < 2; nch++) {                     \
      short8_t sf[4];                                                         \
      _Pragma("unroll") for (int mf = 0; mf < 4; mf++)                        \
        sf[mf] = *(const short8_t*)(&Slds[BUF][(mf * 16 + lm) * PITCH +       \
                                              nch * 32 + lg * 8]);            \
      _Pragma("unroll") for (int cf = 0; cf < 2; cf++)                        \
        _Pragma("unroll") for (int mf = 0; mf < 4; mf++)                      \
          acc[cf][mf] = __builtin_amdgcn_mfma_f32_16x16x32_bf16(              \
              vc[cf][nch], sf[mf], acc[cf][mf], 0, 0, 0);                     \
    }                                                                         \
    __builtin_amdgcn_s_setprio(0);                                            \
  }

#pragma unroll 1
  for (int t = 0; t < 64; t += 2) {
    AITER(t, kA, kB, 0)
    AITER(t + 1, kB, kA, 1)
  }
#undef AITER

  // denominator: fold lane groups, then 4 waves via LDS
#pragma unroll
  for (int mf = 0; mf < 4; mf++) {
    float v = dsum[mf];
    v += __shfl_xor(v, 16);
    v += __shfl_xor(v, 32);
    if (lane < 16) dlds[w][mf * 16 + lane] = v;
  }
  __syncthreads();

  const float g0 = gamma[0];
  float rden[4];
#pragma unroll
  for (int mf = 0; mf < 4; mf++) {
    const int mloc = mf * 16 + lm;
    float den = dlds[0][mloc] + dlds[1][mloc] + dlds[2][mloc] + dlds[3][mloc];
    den = den > 1e-12f ? den : 1e-12f;
    rden[mf] = 1.0f / den;
  }

  const float* xb = x + (size_t)b * NC * NN;
  float* ob = out + (size_t)b * NC * NN;
#pragma unroll
  for (int cf = 0; cf < 2; cf++) {
#pragma unroll
    for (int i = 0; i < 4; i++) {
      const int c = ch * 128 + w * 32 + cf * 16 + lg * 4 + i;
#pragma unroll
      for (int mf = 0; mf < 4; mf++) {
        const int m = m0 + mf * 16 + lm;
        ob[(size_t)c * NN + m] = g0 * acc[cf][mf][i] * rden[mf] + xb[(size_t)c * NN + m];
      }
    }
  }
}

extern "C" void kernel_launch(void* const* d_in, const int* in_sizes, int n_in,
                              void* d_out, int out_size, void* d_ws, size_t ws_size,
                              hipStream_t stream) {
  const float* x     = (const float*)d_in[0];
  const float* Wq    = (const float*)d_in[1];
  const float* bq    = (const float*)d_in[2];
  const float* Wk    = (const float*)d_in[3];
  const float* bk    = (const float*)d_in[4];
  const float* Wv    = (const float*)d_in[5];
  const float* bv    = (const float*)d_in[6];
  const float* gamma = (const float*)d_in[7];
  float* out = (float*)d_out;

  // ws (bf16): Wbf[320][256], xT[4][4096][256], Qt[4][4096][32], Kt[..], Vt[4][256][4096]
  unsigned short* Wbf = (unsigned short*)d_ws;
  unsigned short* xT  = Wbf + (size_t)320 * NC;
  unsigned short* Qt  = xT + (size_t)NB * NN * NC;
  unsigned short* Kt  = Qt + (size_t)NB * NN * NCR;
  unsigned short* Vt  = Kt + (size_t)NB * NN * NCR;

  hipLaunchKernelGGL(pack_w_kernel, dim3(320), dim3(64), 0, stream,
                     Wq, Wk, Wv, Wbf);
  hipLaunchKernelGGL(xpose_kernel, dim3(2048), dim3(256), 0, stream, x, xT);
  hipLaunchKernelGGL(qkv_kernel, dim3(512), dim3(256), 0, stream,
                     xT, Wbf, bq, bk, bv, Qt, Kt, Vt);
  hipLaunchKernelGGL(attn_kernel, dim3(512), dim3(256), 0, stream,
                     Qt, Kt, Vt, x, gamma, out);
}

// Round 5
// 102.317 us; speedup vs baseline: 2.0694x; 1.0000x over previous
//
#include <hip/hip_runtime.h>
#include <hip/hip_bf16.h>

#define NB 4
#define NC 256
#define NN 4096
#define NCR 32
#define PITCH 72   // shorts; 144B rows -> 2-way max aliasing (free per m136)

typedef __attribute__((ext_vector_type(8))) short short8_t;
typedef __attribute__((ext_vector_type(4))) float f32x4;
typedef __attribute__((ext_vector_type(2))) int int2_t;
typedef __attribute__((ext_vector_type(4))) int int4_t;
typedef __attribute__((ext_vector_type(4))) float float4_t;

static __device__ __forceinline__ unsigned short f2bf(float f) {
  unsigned u = __builtin_bit_cast(unsigned, f);
  u += 0x7FFFu + ((u >> 16) & 1u);
  return (unsigned short)(u >> 16);
}

static __device__ __forceinline__ unsigned cvt_pk(float lo, float hi) {
  unsigned r;
  asm("v_cvt_pk_bf16_f32 %0, %1, %2" : "=v"(r) : "v"(lo), "v"(hi));
  return r;
}

// LDS-only barrier: do NOT drain vmcnt (keeps global V/K prefetches in
// flight across the barrier — __syncthreads would force vmcnt(0)).
static __device__ __forceinline__ void lds_barrier() {
  asm volatile("s_waitcnt lgkmcnt(0)\n\ts_barrier" ::: "memory");
}

// ---------------------------------------------------------------------------
// Kernel 0: one-time W pack f32 -> bf16. rows [0,32)=Wq, [32,64)=Wk, [64,320)=Wv
// ---------------------------------------------------------------------------
__global__ __launch_bounds__(64) void pack_w_kernel(
    const float* __restrict__ Wq, const float* __restrict__ Wk,
    const float* __restrict__ Wv, unsigned short* __restrict__ Wbf)
{
  const int row = blockIdx.x;
  const int t = threadIdx.x;
  const float* src = row < 32 ? Wq + (size_t)row * NC
                   : (row < 64 ? Wk + (size_t)(row - 32) * NC
                               : Wv + (size_t)(row - 64) * NC);
  float4_t v = *(const float4_t*)(src + t * 4);
  int2_t p;
  p[0] = cvt_pk(v[0], v[1]);
  p[1] = cvt_pk(v[2], v[3]);
  *(int2_t*)(Wbf + (size_t)row * NC + t * 4) = p;
}

// ---------------------------------------------------------------------------
// Kernel 0b: transpose+cast x[b][k][m] f32 -> xT[b][m][k] bf16.
// ---------------------------------------------------------------------------
__global__ __launch_bounds__(256) void xpose_kernel(
    const float* __restrict__ x, unsigned short* __restrict__ xT)
{
  __shared__ float tile[32][65];
  const int bid = blockIdx.x;
  const int mt = bid & 63, kt = (bid >> 6) & 7, b = bid >> 9;
  const int m0 = mt * 64, k0 = kt * 32;
  const int tid = threadIdx.x;

  const float* xb = x + (size_t)b * NC * NN + (size_t)k0 * NN + m0;
#pragma unroll
  for (int p = 0; p < 8; p++) {
    const int r = p * 4 + (tid >> 6);
    tile[r][tid & 63] = xb[(size_t)r * NN + (tid & 63)];
  }
  __syncthreads();

  const int m = tid >> 2, kq = (tid & 3) * 8;
  int4_t o;
#pragma unroll
  for (int j = 0; j < 4; j++)
    o[j] = cvt_pk(tile[kq + 2 * j][m], tile[kq + 2 * j + 1][m]);
  *(int4_t*)(xT + ((size_t)b * NN + m0 + m) * NC + k0 + kq) = o;
}

// ---------------------------------------------------------------------------
// Kernel 1: QKV projection — pure streaming GEMM, no LDS.
// ---------------------------------------------------------------------------
__global__ __launch_bounds__(256, 2) void qkv_kernel(
    const unsigned short* __restrict__ xT, const unsigned short* __restrict__ Wbf,
    const float* __restrict__ bq, const float* __restrict__ bk,
    const float* __restrict__ bv,
    unsigned short* __restrict__ Qt, unsigned short* __restrict__ Kt,
    unsigned short* __restrict__ Vt)
{
  const int bid = blockIdx.x;
  const int b   = bid >> 7;
  const int m0  = (bid & 127) * 32;
  const int tid = threadIdx.x;
  const int w    = tid >> 6;
  const int lane = tid & 63;
  const int lg   = lane >> 4;
  const int lm   = lane & 15;

  const unsigned short* xrow0 = xT + ((size_t)b * NN + m0 + lm) * NC + lg * 8;
  const unsigned short* xrow1 = xrow0 + 16 * NC;
  const unsigned short* wrow  = Wbf + (size_t)(w * 80 + lm) * NC + lg * 8;

  const f32x4 zero4 = {0.f, 0.f, 0.f, 0.f};
  f32x4 acc[5][2];
#pragma unroll
  for (int df = 0; df < 5; df++)
#pragma unroll
    for (int mf = 0; mf < 2; mf++) acc[df][mf] = zero4;

#pragma unroll
  for (int kc = 0; kc < 8; kc++) {
    const short8_t xf0 = *(const short8_t*)(xrow0 + kc * 32);
    const short8_t xf1 = *(const short8_t*)(xrow1 + kc * 32);
#pragma unroll
    for (int df = 0; df < 5; df++) {
      const short8_t wf = *(const short8_t*)(wrow + (size_t)df * 16 * NC + kc * 32);
      acc[df][0] = __builtin_amdgcn_mfma_f32_16x16x32_bf16(xf0, wf, acc[df][0], 0, 0, 0);
      acc[df][1] = __builtin_amdgcn_mfma_f32_16x16x32_bf16(xf1, wf, acc[df][1], 0, 0, 0);
    }
  }

#pragma unroll
  for (int df = 0; df < 5; df++) {
    const int dbase = w * 80 + df * 16;
    if (dbase < 64) {
      const bool isq = dbase < 32;
      const float bia = isq ? bq[dbase + lm] : bk[dbase - 32 + lm];
      unsigned short* dst = isq ? Qt : Kt;
      const int dcol = (isq ? dbase : dbase - 32) + lm;
#pragma unroll
      for (int mf = 0; mf < 2; mf++)
#pragma unroll
        for (int i = 0; i < 4; i++) {
          const int m = m0 + mf * 16 + lg * 4 + i;
          dst[((size_t)b * NN + m) * NCR + dcol] = f2bf(acc[df][mf][i] + bia);
        }
    } else {
      const int c = dbase - 64 + lm;
      const float bia = bv[c];
#pragma unroll
      for (int mf = 0; mf < 2; mf++) {
        int2_t p;
        p[0] = cvt_pk(acc[df][mf][0] + bia, acc[df][mf][1] + bia);
        p[1] = cvt_pk(acc[df][mf][2] + bia, acc[df][mf][3] + bia);
        *(int2_t*)(Vt + ((size_t)b * NC + c) * NN + m0 + mf * 16 + lg * 4) = p;
      }
    }
  }
}

// ---------------------------------------------------------------------------
// Kernel 2: streaming attention, c-split, register-double-buffered V and K,
// LDS-only barrier (global loads stay in flight across iterations).
// Grid 512 = batch x m-tile x c-half, 4 waves, 2 blocks/CU.
// ---------------------------------------------------------------------------
__global__ __launch_bounds__(256, 2) void attn_kernel(
    const unsigned short* __restrict__ Qt, const unsigned short* __restrict__ Kt,
    const unsigned short* __restrict__ Vt, const float* __restrict__ x,
    const float* __restrict__ gamma, float* __restrict__ out)
{
  __shared__ unsigned short Slds[2][64 * PITCH];  // 18.4 KB
  __shared__ float dlds[4][64];

  const int bid = blockIdx.x;
  const int xcd = bid & 7;
  const int b   = xcd >> 1;          // batch pinned to an XCD pair slot
  const int ch  = xcd & 1;           // c-half
  const int m0  = (bid >> 3) * 64;   // 64 m-tiles per (b, ch)
  const int tid = threadIdx.x;
  const int w    = tid >> 6;
  const int lane = tid & 63;
  const int lg   = lane >> 4;
  const int lm   = lane & 15;

  const unsigned short* Qb = Qt + (size_t)b * NN * NCR;
  const unsigned short* Kp = Kt + (size_t)b * NN * NCR +
                             (size_t)(w * 16 + lm) * NCR + lg * 8;
  const unsigned short* pV[2];
#pragma unroll
  for (int cf = 0; cf < 2; cf++)
    pV[cf] = Vt + ((size_t)b * NC + ch * 128 + w * 32 + cf * 16 + lm) * NN + lg * 8;

  short8_t qf[4];
#pragma unroll
  for (int mf = 0; mf < 4; mf++)
    qf[mf] = *(const short8_t*)(Qb + (size_t)(m0 + mf * 16 + lm) * NCR + lg * 8);

  const f32x4 zero4 = {0.f, 0.f, 0.f, 0.f};
  f32x4 acc[2][4];
#pragma unroll
  for (int cf = 0; cf < 2; cf++)
#pragma unroll
    for (int mf = 0; mf < 4; mf++) acc[cf][mf] = zero4;
  float dsum[4] = {0.f, 0.f, 0.f, 0.f};

  // prologue: tile-0 K and V fragments
  short8_t kA, kB, vA[2][2], vB[2][2];
  kA = *(const short8_t*)(Kp);
#pragma unroll
  for (int cf = 0; cf < 2; cf++) {
    vA[cf][0] = *(const short8_t*)(pV[cf]);
    vA[cf][1] = *(const short8_t*)(pV[cf] + 32);
  }

  const int swofs = w * 16 + lg * 4;

#define AITER(T, KC, KN, VC, VN, BUF) {                                       \
    const int n1 = (((T) + 1) & 63) * 64;                                     \
    /* prefetch next-iter K and V; consumed only after the NEXT barrier */    \
    KN = *(const short8_t*)(Kp + (size_t)n1 * NCR);                           \
    _Pragma("unroll") for (int cf = 0; cf < 2; cf++) {                        \
      VN[cf][0] = *(const short8_t*)(pV[cf] + n1);                            \
      VN[cf][1] = *(const short8_t*)(pV[cf] + n1 + 32);                       \
    }                                                                         \
    _Pragma("unroll") for (int mf = 0; mf < 4; mf++) {                        \
      f32x4 s = __builtin_amdgcn_mfma_f32_16x16x32_bf16(KC, qf[mf], zero4, 0, 0, 0); \
      float s0 = fmaxf(s[0], 0.f), s1 = fmaxf(s[1], 0.f);                     \
      float s2 = fmaxf(s[2], 0.f), s3 = fmaxf(s[3], 0.f);                     \
      dsum[mf] += (s0 + s1) + (s2 + s3);                                      \
      int2_t p; p[0] = cvt_pk(s0, s1); p[1] = cvt_pk(s2, s3);                 \
      *(int2_t*)(&Slds[BUF][(mf * 16 + lm) * PITCH + swofs]) = p;             \
    }                                                                         \
    lds_barrier();                                                            \
    __builtin_amdgcn_s_setprio(1);                                            \
    _Pragma("unroll") for (int nch = 0; nch < 2; nch++) {                     \
      short8_t sf[4];                                                         \
      _Pragma("unroll") for (int mf = 0; mf < 4; mf++)                        \
        sf[mf] = *(const short8_t*)(&Slds[BUF][(mf * 16 + lm) * PITCH +       \
                                              nch * 32 + lg * 8]);            \
      _Pragma("unroll") for (int cf = 0; cf < 2; cf++)                        \
        _Pragma("unroll") for (int mf = 0; mf < 4; mf++)                      \
          acc[cf][mf] = __builtin_amdgcn_mfma_f32_16x16x32_bf16(              \
              VC[cf][nch], sf[mf], acc[cf][mf], 0, 0, 0);                     \
    }                                                                         \
    __builtin_amdgcn_s_setprio(0);                                            \
  }

#pragma unroll 1
  for (int t = 0; t < 64; t += 2) {
    AITER(t, kA, kB, vA, vB, 0)
    AITER(t + 1, kB, kA, vB, vA, 1)
  }
#undef AITER

  // denominator: fold lane groups, then 4 waves via LDS
#pragma unroll
  for (int mf = 0; mf < 4; mf++) {
    float v = dsum[mf];
    v += __shfl_xor(v, 16);
    v += __shfl_xor(v, 32);
    if (lane < 16) dlds[w][mf * 16 + lane] = v;
  }
  __syncthreads();

  const float g0 = gamma[0];
  float rden[4];
#pragma unroll
  for (int mf = 0; mf < 4; mf++) {
    const int mloc = mf * 16 + lm;
    float den = dlds[0][mloc] + dlds[1][mloc] + dlds[2][mloc] + dlds[3][mloc];
    den = den > 1e-12f ? den : 1e-12f;
    rden[mf] = 1.0f / den;
  }

  const float* xb = x + (size_t)b * NC * NN;
  float* ob = out + (size_t)b * NC * NN;
#pragma unroll
  for (int cf = 0; cf < 2; cf++) {
#pragma unroll
    for (int i = 0; i < 4; i++) {
      const int c = ch * 128 + w * 32 + cf * 16 + lg * 4 + i;
#pragma unroll
      for (int mf = 0; mf < 4; mf++) {
        const int m = m0 + mf * 16 + lm;
        ob[(size_t)c * NN + m] = g0 * acc[cf][mf][i] * rden[mf] + xb[(size_t)c * NN + m];
      }
    }
  }
}

extern "C" void kernel_launch(void* const* d_in, const int* in_sizes, int n_in,
                              void* d_out, int out_size, void* d_ws, size_t ws_size,
                              hipStream_t stream) {
  const float* x     = (const float*)d_in[0];
  const float* Wq    = (const float*)d_in[1];
  const float* bq    = (const float*)d_in[2];
  const float* Wk    = (const float*)d_in[3];
  const float* bk    = (const float*)d_in[4];
  const float* Wv    = (const float*)d_in[5];
  const float* bv    = (const float*)d_in[6];
  const float* gamma = (const float*)d_in[7];
  float* out = (float*)d_out;

  // ws (bf16): Wbf[320][256], xT[4][4096][256], Qt[4][4096][32], Kt[..], Vt[4][256][4096]
  unsigned short* Wbf = (unsigned short*)d_ws;
  unsigned short* xT  = Wbf + (size_t)320 * NC;
  unsigned short* Qt  = xT + (size_t)NB * NN * NC;
  unsigned short* Kt  = Qt + (size_t)NB * NN * NCR;
  unsigned short* Vt  = Kt + (size_t)NB * NN * NCR;

  hipLaunchKernelGGL(pack_w_kernel, dim3(320), dim3(64), 0, stream,
                     Wq, Wk, Wv, Wbf);
  hipLaunchKernelGGL(xpose_kernel, dim3(2048), dim3(256), 0, stream, x, xT);
  hipLaunchKernelGGL(qkv_kernel, dim3(512), dim3(256), 0, stream,
                     xT, Wbf, bq, bk, bv, Qt, Kt, Vt);
  hipLaunchKernelGGL(attn_kernel, dim3(512), dim3(256), 0, stream,
                     Qt, Kt, Vt, x, gamma, out);
}